// Round 1
// baseline (282.325 us; speedup 1.0000x reference)
//
#include <hip/hip_runtime.h>
#include <hip/hip_bf16.h>

typedef unsigned short u16;
typedef __attribute__((ext_vector_type(8))) short bhalf8;   // 8 x bf16 (4 VGPRs)
typedef __attribute__((ext_vector_type(4))) float f32x4;    // MFMA accumulator

#define MFMA16(a, b, c) __builtin_amdgcn_mfma_f32_16x16x32_bf16((a), (b), (c), 0, 0, 0)

// ---- constants for this problem ----
#define BB 2
#define SS 2048
#define DD 512
#define HH 8
#define HD 64
#define NT (BB * SS)          // 4096 tokens

// fp32 -> bf16 round-to-nearest-even (no NaN path needed here)
__device__ __forceinline__ u16 f2b(float f) {
    unsigned u = __builtin_bit_cast(unsigned, f);
    unsigned r = (u + 0x7fffu + ((u >> 16) & 1u)) >> 16;
    return (u16)r;
}

// ---------------------------------------------------------------------------
// Weight transpose: src fp32 [R][C] (optionally batched) -> dst bf16 [C][R]
// ---------------------------------------------------------------------------
__global__ __launch_bounds__(256) void k_transpose(const float* __restrict__ src,
                                                   u16* __restrict__ dst,
                                                   int R, int C,
                                                   int srcBatchStride, int dstBatchStride) {
    __shared__ float tile[32][33];
    int bz = blockIdx.z;
    src += (size_t)bz * srcBatchStride;
    dst += (size_t)bz * dstBatchStride;
    int tx = threadIdx.x, ty = threadIdx.y;   // (32, 8)
    int c = blockIdx.x * 32 + tx;
#pragma unroll
    for (int i = 0; i < 4; i++) {
        int r = blockIdx.y * 32 + ty + i * 8;
        tile[ty + i * 8][tx] = src[(size_t)r * C + c];
    }
    __syncthreads();
    int r2 = blockIdx.y * 32 + tx;
#pragma unroll
    for (int i = 0; i < 4; i++) {
        int c2 = blockIdx.x * 32 + ty + i * 8;
        dst[(size_t)c2 * R + r2] = f2b(tile[tx][ty + i * 8]);
    }
}

__global__ void k_concat_bias(const float* __restrict__ bq, const float* __restrict__ bk,
                              const float* __restrict__ bv, float* __restrict__ out) {
    int i = blockIdx.x * 256 + threadIdx.x;
    if (i < 512) out[i] = bq[i];
    else if (i < 1024) out[i] = bk[i - 512];
    else if (i < 1536) out[i] = bv[i - 1024];
}

// ---------------------------------------------------------------------------
// LayerNorm: one wave per row of 512 fp32, writes bf16
// ---------------------------------------------------------------------------
__global__ __launch_bounds__(256) void k_layernorm(const float* __restrict__ x,
                                                   const float* __restrict__ g,
                                                   const float* __restrict__ be,
                                                   u16* __restrict__ out) {
    int wave = threadIdx.x >> 6, lane = threadIdx.x & 63;
    int row = blockIdx.x * 4 + wave;
    const float* xr = x + (size_t)row * DD;
    int c = lane * 8;
    float4 v0 = *(const float4*)(xr + c);
    float4 v1 = *(const float4*)(xr + c + 4);
    float s  = v0.x + v0.y + v0.z + v0.w + v1.x + v1.y + v1.z + v1.w;
    float sq = v0.x*v0.x + v0.y*v0.y + v0.z*v0.z + v0.w*v0.w
             + v1.x*v1.x + v1.y*v1.y + v1.z*v1.z + v1.w*v1.w;
#pragma unroll
    for (int m = 1; m < 64; m <<= 1) {
        s  += __shfl_xor(s, m);
        sq += __shfl_xor(sq, m);
    }
    float mean = s * (1.0f / DD);
    float var  = sq * (1.0f / DD) - mean * mean;
    float rstd = rsqrtf(var + 1e-5f);
    float4 g0 = *(const float4*)(g + c);
    float4 g1 = *(const float4*)(g + c + 4);
    float4 b0 = *(const float4*)(be + c);
    float4 b1 = *(const float4*)(be + c + 4);
    union { bhalf8 v; u16 u[8]; } pk;
    float xv[8] = {v0.x, v0.y, v0.z, v0.w, v1.x, v1.y, v1.z, v1.w};
    float gv[8] = {g0.x, g0.y, g0.z, g0.w, g1.x, g1.y, g1.z, g1.w};
    float bv[8] = {b0.x, b0.y, b0.z, b0.w, b1.x, b1.y, b1.z, b1.w};
#pragma unroll
    for (int i = 0; i < 8; i++) pk.u[i] = f2b((xv[i] - mean) * rstd * gv[i] + bv[i]);
    *(bhalf8*)(out + (size_t)row * DD + c) = pk.v;
}

// ---------------------------------------------------------------------------
// Generic bf16 MFMA GEMM:  C[M,N] = A[M,K] * Bt[N,K]^T + bias, epilogue modes
//   mode 0: scatter to q/k/v [B,H,S,HD] bf16
//   mode 1: out fp32 = val + resid
//   mode 2: out bf16 = relu(val)
// Block: 256 threads (4 waves, 2x2), tile 64x64, BK=32.
// ---------------------------------------------------------------------------
__global__ __launch_bounds__(256) void k_gemm_bt(const u16* __restrict__ A,
                                                 const u16* __restrict__ Bt,
                                                 const float* __restrict__ bias,
                                                 int M, int N, int K, int mode,
                                                 const float* __restrict__ resid,
                                                 float* __restrict__ outF,
                                                 u16* __restrict__ outB,
                                                 u16* __restrict__ qd, u16* __restrict__ kd,
                                                 u16* __restrict__ vd) {
    __shared__ u16 As[64 * 32];
    __shared__ u16 Bs[64 * 32];
    int t = threadIdx.x;
    int wave = t >> 6, lane = t & 63, quad = lane >> 4, l16 = lane & 15;
    int wr = wave >> 1, wc = wave & 1;
    int m0 = blockIdx.y * 64, n0 = blockIdx.x * 64;

    f32x4 acc[2][2] = {{{0.f,0.f,0.f,0.f},{0.f,0.f,0.f,0.f}},
                       {{0.f,0.f,0.f,0.f},{0.f,0.f,0.f,0.f}}};

    int ar = t >> 2;               // 0..63
    int ac = (t & 3) * 8;          // 0,8,16,24
    const u16* Ap = A  + (size_t)(m0 + ar) * K + ac;
    const u16* Bp = Bt + (size_t)(n0 + ar) * K + ac;

    for (int k0 = 0; k0 < K; k0 += 32) {
        __syncthreads();
        *(bhalf8*)&As[ar * 32 + ac] = *(const bhalf8*)(Ap + k0);
        *(bhalf8*)&Bs[ar * 32 + ac] = *(const bhalf8*)(Bp + k0);
        __syncthreads();
        bhalf8 af0 = *(bhalf8*)&As[(wr * 32 + l16) * 32 + quad * 8];
        bhalf8 af1 = *(bhalf8*)&As[(wr * 32 + 16 + l16) * 32 + quad * 8];
        bhalf8 bf0 = *(bhalf8*)&Bs[(wc * 32 + l16) * 32 + quad * 8];
        bhalf8 bf1 = *(bhalf8*)&Bs[(wc * 32 + 16 + l16) * 32 + quad * 8];
        acc[0][0] = MFMA16(af0, bf0, acc[0][0]);
        acc[0][1] = MFMA16(af0, bf1, acc[0][1]);
        acc[1][0] = MFMA16(af1, bf0, acc[1][0]);
        acc[1][1] = MFMA16(af1, bf1, acc[1][1]);
    }

#pragma unroll
    for (int mi = 0; mi < 2; mi++)
#pragma unroll
        for (int ni = 0; ni < 2; ni++) {
            f32x4 a = acc[mi][ni];
            int gc = n0 + wc * 32 + ni * 16 + l16;
            float bsv = bias[gc];
#pragma unroll
            for (int r = 0; r < 4; r++) {
                int gr = m0 + wr * 32 + mi * 16 + quad * 4 + r;
                float val = a[r] + bsv;
                if (mode == 0) {
                    int cc = gc & 511, mm = gc >> 9;
                    int hh = cc >> 6, e = cc & 63;
                    int b = gr >> 11, s = gr & 2047;
                    u16* dst = (mm == 0) ? qd : (mm == 1) ? kd : vd;
                    dst[(size_t)(((b << 3) + hh) * SS + s) * HD + e] = f2b(val);
                } else if (mode == 1) {
                    size_t idx = (size_t)gr * N + gc;
                    outF[idx] = val + resid[idx];
                } else {
                    outB[(size_t)gr * N + gc] = f2b(fmaxf(val, 0.0f));
                }
            }
        }
}

// ---------------------------------------------------------------------------
// Flash-style attention (no scale, no mask, full softmax over S):
//   grid (B*H, S/64); block 256 = 4 waves; wave handles 16 q rows.
//   q,k,v bf16 [B,H,S,64]; out bf16 [B,S,D] (heads concatenated).
// ---------------------------------------------------------------------------
__global__ __launch_bounds__(256) void k_attention(const u16* __restrict__ q,
                                                   const u16* __restrict__ k,
                                                   const u16* __restrict__ v,
                                                   u16* __restrict__ o) {
    __shared__ u16 Ks[64 * 72];
    __shared__ u16 Vt[64 * 72];
    __shared__ u16 Pw[4][16 * 72];
    int bh = blockIdx.x;     // 0..15
    int qt = blockIdx.y;     // 0..31
    int t = threadIdx.x, wave = t >> 6, lane = t & 63, quad = lane >> 4, l16 = lane & 15;
    const u16* qb = q + (size_t)bh * SS * HD;
    const u16* kb = k + (size_t)bh * SS * HD;
    const u16* vb = v + (size_t)bh * SS * HD;

    int srow = qt * 64 + wave * 16 + l16;
    bhalf8 qf0 = *(const bhalf8*)(qb + (size_t)srow * HD + quad * 8);
    bhalf8 qf1 = *(const bhalf8*)(qb + (size_t)srow * HD + 32 + quad * 8);

    f32x4 oacc[4] = {{0.f,0.f,0.f,0.f},{0.f,0.f,0.f,0.f},{0.f,0.f,0.f,0.f},{0.f,0.f,0.f,0.f}};
    float mrun[4], lrun[4];
#pragma unroll
    for (int r = 0; r < 4; r++) { mrun[r] = -1e30f; lrun[r] = 0.f; }

    int sr  = t >> 2,  sc0 = (t & 3) * 16;   // K staging
    int vk  = t & 63,  ve0 = (t >> 6) * 16;  // V-transpose staging
    u16* pw = &Pw[wave][0];

    for (int kv0 = 0; kv0 < SS; kv0 += 64) {
        __syncthreads();
        *(bhalf8*)&Ks[sr * 72 + sc0]     = *(const bhalf8*)(kb + (size_t)(kv0 + sr) * HD + sc0);
        *(bhalf8*)&Ks[sr * 72 + sc0 + 8] = *(const bhalf8*)(kb + (size_t)(kv0 + sr) * HD + sc0 + 8);
        bhalf8 va  = *(const bhalf8*)(vb + (size_t)(kv0 + vk) * HD + ve0);
        bhalf8 vb8 = *(const bhalf8*)(vb + (size_t)(kv0 + vk) * HD + ve0 + 8);
#pragma unroll
        for (int j = 0; j < 8; j++) {
            Vt[(ve0 + j) * 72 + vk]     = (u16)va[j];
            Vt[(ve0 + 8 + j) * 72 + vk] = (u16)vb8[j];
        }
        __syncthreads();

        // scores: 16 q rows x 64 kv cols
        f32x4 sacc[4] = {{0.f,0.f,0.f,0.f},{0.f,0.f,0.f,0.f},{0.f,0.f,0.f,0.f},{0.f,0.f,0.f,0.f}};
#pragma unroll
        for (int nt = 0; nt < 4; nt++) {
            bhalf8 kf0 = *(bhalf8*)&Ks[(nt * 16 + l16) * 72 + quad * 8];
            bhalf8 kf1 = *(bhalf8*)&Ks[(nt * 16 + l16) * 72 + 32 + quad * 8];
            sacc[nt] = MFMA16(qf0, kf0, sacc[nt]);
            sacc[nt] = MFMA16(qf1, kf1, sacc[nt]);
        }

        // online softmax over this 64-col tile
        float tmax[4], rsum[4], alpha[4];
#pragma unroll
        for (int r = 0; r < 4; r++) {
            tmax[r] = fmaxf(fmaxf(sacc[0][r], sacc[1][r]), fmaxf(sacc[2][r], sacc[3][r]));
        }
#pragma unroll
        for (int m = 1; m < 16; m <<= 1)
#pragma unroll
            for (int r = 0; r < 4; r++) tmax[r] = fmaxf(tmax[r], __shfl_xor(tmax[r], m));
#pragma unroll
        for (int r = 0; r < 4; r++) {
            float mn = fmaxf(mrun[r], tmax[r]);
            alpha[r] = __expf(mrun[r] - mn);
            mrun[r] = mn;
            rsum[r] = 0.f;
        }
#pragma unroll
        for (int nt = 0; nt < 4; nt++)
#pragma unroll
            for (int r = 0; r < 4; r++) {
                float p = __expf(sacc[nt][r] - mrun[r]);
                sacc[nt][r] = p;
                rsum[r] += p;
            }
#pragma unroll
        for (int m = 1; m < 16; m <<= 1)
#pragma unroll
            for (int r = 0; r < 4; r++) rsum[r] += __shfl_xor(rsum[r], m);
#pragma unroll
        for (int r = 0; r < 4; r++) lrun[r] = lrun[r] * alpha[r] + rsum[r];
#pragma unroll
        for (int et = 0; et < 4; et++)
#pragma unroll
            for (int r = 0; r < 4; r++) oacc[et][r] *= alpha[r];

        // P: C-layout -> LDS -> A-layout (wave-local region)
#pragma unroll
        for (int nt = 0; nt < 4; nt++)
#pragma unroll
            for (int r = 0; r < 4; r++)
                pw[(quad * 4 + r) * 72 + nt * 16 + l16] = f2b(sacc[nt][r]);
        asm volatile("s_waitcnt lgkmcnt(0)" ::: "memory");

#pragma unroll
        for (int ks = 0; ks < 2; ks++) {
            bhalf8 pa = *(bhalf8*)&pw[l16 * 72 + ks * 32 + quad * 8];
#pragma unroll
            for (int et = 0; et < 4; et++) {
                bhalf8 vf = *(bhalf8*)&Vt[(et * 16 + l16) * 72 + ks * 32 + quad * 8];
                oacc[et] = MFMA16(pa, vf, oacc[et]);
            }
        }
    }

    int b = bh >> 3, h = bh & 7;
    float inv[4];
#pragma unroll
    for (int r = 0; r < 4; r++) inv[r] = 1.0f / lrun[r];
#pragma unroll
    for (int et = 0; et < 4; et++)
#pragma unroll
        for (int r = 0; r < 4; r++) {
            int s = qt * 64 + wave * 16 + quad * 4 + r;
            int col = h * HD + et * 16 + l16;
            o[((size_t)b * SS + s) * DD + col] = f2b(oacc[et][r] * inv[r]);
        }
}

// ---------------------------------------------------------------------------
// Launch
// ---------------------------------------------------------------------------
extern "C" void kernel_launch(void* const* d_in, const int* in_sizes, int n_in,
                              void* d_out, int out_size, void* d_ws, size_t ws_size,
                              hipStream_t stream) {
    const float* x   = (const float*)d_in[0];
    const float* Wq  = (const float*)d_in[1];
    const float* bq  = (const float*)d_in[2];
    const float* Wk  = (const float*)d_in[3];
    const float* bk  = (const float*)d_in[4];
    const float* Wv  = (const float*)d_in[5];
    const float* bv  = (const float*)d_in[6];
    const float* Wp  = (const float*)d_in[7];
    const float* bp  = (const float*)d_in[8];
    const float* W1  = (const float*)d_in[9];
    const float* b1  = (const float*)d_in[10];
    const float* W2  = (const float*)d_in[11];
    const float* b2  = (const float*)d_in[12];
    const float* g1  = (const float*)d_in[13];
    const float* be1 = (const float*)d_in[14];
    const float* g2  = (const float*)d_in[15];
    const float* be2 = (const float*)d_in[16];

    char* ws = (char*)d_ws;
    // ws layout (bytes)
    u16*   WqkvT   = (u16*)(ws + 0);                    // 1536*512*2  = 1,572,864
    u16*   WpT     = (u16*)(ws + 1572864);              //  512*512*2  =   524,288
    u16*   W1T     = (u16*)(ws + 2097152);              // 2048*512*2  = 2,097,152
    u16*   W2T     = (u16*)(ws + 4194304);              //  512*2048*2 = 2,097,152
    float* biasqkv = (float*)(ws + 6291456);            // 1536*4
    u16*   xn      = (u16*)(ws + 6297600);              // 4096*512*2  = 4,194,304
    u16*   qB      = (u16*)(ws + 10491904);             // 4,194,304
    u16*   kB      = (u16*)(ws + 14686208);             // 4,194,304
    u16*   vB      = (u16*)(ws + 18880512);             // 4,194,304
    u16*   oc      = (u16*)(ws + 23074816);             // 4,194,304
    float* x1      = (float*)(ws + 27269120);           // 4096*512*4  = 8,388,608
    u16*   xn2     = (u16*)(ws + 35657728);             // 4,194,304
    u16*   hbuf    = (u16*)(ws + 39852032);             // 4096*2048*2 = 16,777,216  (end 56,629,248)

    dim3 tb(32, 8);
    // Wq/Wk/Wv: per head [512,64] -> [64,512], batch 8
    k_transpose<<<dim3(2, 16, 8), tb, 0, stream>>>(Wq, WqkvT,               512, 64, 512 * 64, 64 * 512);
    k_transpose<<<dim3(2, 16, 8), tb, 0, stream>>>(Wk, WqkvT + 512 * 512,   512, 64, 512 * 64, 64 * 512);
    k_transpose<<<dim3(2, 16, 8), tb, 0, stream>>>(Wv, WqkvT + 1024 * 512,  512, 64, 512 * 64, 64 * 512);
    k_transpose<<<dim3(16, 16, 1), tb, 0, stream>>>(Wp, WpT,   512, 512,  0, 0);
    k_transpose<<<dim3(64, 16, 1), tb, 0, stream>>>(W1, W1T,   512, 2048, 0, 0);
    k_transpose<<<dim3(16, 64, 1), tb, 0, stream>>>(W2, W2T,  2048, 512,  0, 0);
    k_concat_bias<<<6, 256, 0, stream>>>(bq, bk, bv, biasqkv);

    // LN1
    k_layernorm<<<NT / 4, 256, 0, stream>>>(x, g1, be1, xn);
    // QKV projection (M=4096, N=1536, K=512) -> scatter q/k/v
    k_gemm_bt<<<dim3(24, 64), 256, 0, stream>>>(xn, WqkvT, biasqkv, NT, 1536, 512, 0,
                                                nullptr, nullptr, nullptr, qB, kB, vB);
    // attention
    k_attention<<<dim3(BB * HH, SS / 64), 256, 0, stream>>>(qB, kB, vB, oc);
    // output projection + residual -> x1 fp32
    k_gemm_bt<<<dim3(8, 64), 256, 0, stream>>>(oc, WpT, bp, NT, 512, 512, 1,
                                               x, x1, nullptr, nullptr, nullptr, nullptr);
    // LN2
    k_layernorm<<<NT / 4, 256, 0, stream>>>(x1, g2, be2, xn2);
    // MLP1: relu(xn2 @ W1 + b1) -> bf16
    k_gemm_bt<<<dim3(32, 64), 256, 0, stream>>>(xn2, W1T, b1, NT, 2048, 512, 2,
                                                nullptr, nullptr, hbuf, nullptr, nullptr, nullptr);
    // MLP2: x1 + hbuf @ W2 + b2 -> d_out fp32
    k_gemm_bt<<<dim3(8, 64), 256, 0, stream>>>(hbuf, W2T, b2, NT, 512, 2048, 1,
                                               x1, (float*)d_out, nullptr, nullptr, nullptr, nullptr);
}

// Round 2
// 262.316 us; speedup vs baseline: 1.0763x; 1.0763x over previous
//
#include <hip/hip_runtime.h>
#include <hip/hip_bf16.h>

typedef unsigned short u16;
typedef unsigned long long u64t;
typedef __attribute__((ext_vector_type(8))) short bhalf8;   // 8 x bf16 (4 VGPRs)
typedef __attribute__((ext_vector_type(4))) float f32x4;    // MFMA accumulator

#define MFMA16(a, b, c) __builtin_amdgcn_mfma_f32_16x16x32_bf16((a), (b), (c), 0, 0, 0)

#define BB 2
#define SS 2048
#define DD 512
#define HH 8
#define HD 64
#define NT (BB * SS)          // 4096 tokens

__device__ __forceinline__ u16 f2b(float f) {
    unsigned u = __builtin_bit_cast(unsigned, f);
    unsigned r = (u + 0x7fffu + ((u >> 16) & 1u)) >> 16;
    return (u16)r;
}

// async global->LDS, 16B per lane; LDS dest = wave-uniform base + lane*16
__device__ __forceinline__ void gl2lds16(const u16* g, u16* l) {
    u16* gn = (u16*)g;
    __builtin_amdgcn_global_load_lds((__attribute__((address_space(1))) void*)gn,
                                     (__attribute__((address_space(3))) void*)l, 16, 0, 0);
}

// ---------------------------------------------------------------------------
// Fused weight prep: all fp32->bf16 transposes (3072 32x32-tile jobs,
// compile-time dims) + qkv bias concat (6 blocks). One launch replaces 7.
// ---------------------------------------------------------------------------
__global__ __launch_bounds__(256) void k_prep(const float* __restrict__ Wq, const float* __restrict__ Wk,
                                              const float* __restrict__ Wv, const float* __restrict__ Wp,
                                              const float* __restrict__ W1, const float* __restrict__ W2,
                                              const float* __restrict__ bq, const float* __restrict__ bk,
                                              const float* __restrict__ bv,
                                              u16* __restrict__ WqkvT, u16* __restrict__ WpT,
                                              u16* __restrict__ W1T, u16* __restrict__ W2T,
                                              float* __restrict__ biasqkv) {
    int j = blockIdx.x;
    int tx = threadIdx.x, ty = threadIdx.y;   // (32,8)
    if (j >= 3072) {                           // bias concat
        int i = (j - 3072) * 256 + ty * 32 + tx;
        biasqkv[i] = (i < 512) ? bq[i] : (i < 1024) ? bk[i - 512] : bv[i - 1024];
        return;
    }
    __shared__ float tile[32][33];
    const float* src; u16* dst; int R, C, tr, tc;
    if (j < 768) {            // Wq/Wk/Wv per-head [512,64] -> [64,512]
        int m = j >> 8, rem = j & 255, h = rem >> 5, tl = rem & 31;
        tr = tl >> 1; tc = tl & 1;
        src = (m == 0 ? Wq : (m == 1 ? Wk : Wv)) + h * 32768;
        dst = WqkvT + m * 262144 + h * 32768;
        R = 512; C = 64;
    } else if (j < 1024) { int tl = j - 768;  tr = tl >> 4; tc = tl & 15; src = Wp; dst = WpT; R = 512;  C = 512;  }
    else if (j < 2048)   { int tl = j - 1024; tr = tl >> 6; tc = tl & 63; src = W1; dst = W1T; R = 512;  C = 2048; }
    else                 { int tl = j - 2048; tr = tl >> 4; tc = tl & 15; src = W2; dst = W2T; R = 2048; C = 512;  }
    int c = tc * 32 + tx;
#pragma unroll
    for (int i = 0; i < 4; i++)
        tile[ty + i * 8][tx] = src[(size_t)(tr * 32 + ty + i * 8) * C + c];
    __syncthreads();
    int r2 = tr * 32 + tx;
#pragma unroll
    for (int i = 0; i < 4; i++)
        dst[(size_t)(tc * 32 + ty + i * 8) * R + r2] = f2b(tile[tx][ty + i * 8]);
}

// ---------------------------------------------------------------------------
// LayerNorm: one wave per row of 512 fp32, writes bf16
// ---------------------------------------------------------------------------
__global__ __launch_bounds__(256) void k_layernorm(const float* __restrict__ x,
                                                   const float* __restrict__ g,
                                                   const float* __restrict__ be,
                                                   u16* __restrict__ out) {
    int wave = threadIdx.x >> 6, lane = threadIdx.x & 63;
    int row = blockIdx.x * 4 + wave;
    const float* xr = x + (size_t)row * DD;
    int c = lane * 8;
    float4 v0 = *(const float4*)(xr + c);
    float4 v1 = *(const float4*)(xr + c + 4);
    float s  = v0.x + v0.y + v0.z + v0.w + v1.x + v1.y + v1.z + v1.w;
    float sq = v0.x*v0.x + v0.y*v0.y + v0.z*v0.z + v0.w*v0.w
             + v1.x*v1.x + v1.y*v1.y + v1.z*v1.z + v1.w*v1.w;
#pragma unroll
    for (int m = 1; m < 64; m <<= 1) {
        s  += __shfl_xor(s, m);
        sq += __shfl_xor(sq, m);
    }
    float mean = s * (1.0f / DD);
    float var  = sq * (1.0f / DD) - mean * mean;
    float rstd = rsqrtf(var + 1e-5f);
    float4 g0 = *(const float4*)(g + c);
    float4 g1 = *(const float4*)(g + c + 4);
    float4 b0 = *(const float4*)(be + c);
    float4 b1 = *(const float4*)(be + c + 4);
    union { bhalf8 v; u16 u[8]; } pk;
    float xv[8] = {v0.x, v0.y, v0.z, v0.w, v1.x, v1.y, v1.z, v1.w};
    float gv[8] = {g0.x, g0.y, g0.z, g0.w, g1.x, g1.y, g1.z, g1.w};
    float bv[8] = {b0.x, b0.y, b0.z, b0.w, b1.x, b1.y, b1.z, b1.w};
#pragma unroll
    for (int i = 0; i < 8; i++) pk.u[i] = f2b((xv[i] - mean) * rstd * gv[i] + bv[i]);
    *(bhalf8*)(out + (size_t)row * DD + c) = pk.v;
}

// ---------------------------------------------------------------------------
// m97-pattern bf16 GEMM: C[M,N] = A[M,K]*Bt[N,K]^T + bias, 128xBN tile, BK=32,
// global_load_lds width-16 staging (unpadded LDS, wave-uniform chunk bases).
//   mode 0: scatter q/k [bh,s,hd] bf16; V written TRANSPOSED [bh,hd,S] (8B packs)
//   mode 1: out fp32 = val + resid
//   mode 2: out bf16 = relu(val)
// BN=128: waves 2x2 (64x64/wave, 16 MFMA/step); BN=64: waves 4x1 (32x64, 8 MFMA)
// ---------------------------------------------------------------------------
template<int BN, int WR, int WC, int MI, int NI>
__global__ __launch_bounds__(256) void k_gemm(const u16* __restrict__ A, const u16* __restrict__ Bt,
                                              const float* __restrict__ bias,
                                              int M, int N, int K, int mode,
                                              const float* __restrict__ resid,
                                              float* __restrict__ outF, u16* __restrict__ outB,
                                              u16* __restrict__ qd, u16* __restrict__ kd,
                                              u16* __restrict__ vtd) {
    constexpr int WM = 128 / WR;
    constexpr int WN = BN / WC;
    constexpr int NBCH = BN / 16;     // B staging chunks (1KB each)
    __shared__ u16 As[128 * 32];
    __shared__ u16 Bs[BN * 32];
    int t = threadIdx.x;
    int wave = t >> 6, lane = t & 63, quad = lane >> 4, l16 = lane & 15;
    int wr, wc;
    if (WC == 2) { wr = wave >> 1; wc = wave & 1; } else { wr = wave; wc = 0; }
    int m0 = blockIdx.y * 128, n0 = blockIdx.x * BN;

    f32x4 acc[MI][NI] = {};

    int srow = lane >> 2;             // 0..15 within chunk
    int scol = (lane & 3) * 8;        // u16 offset within row
    const u16* Ag = A  + (size_t)(m0 + srow) * K + scol;
    const u16* Bg = Bt + (size_t)(n0 + srow) * K + scol;

    for (int k0 = 0; k0 < K; k0 += 32) {
        __syncthreads();
#pragma unroll
        for (int c = 0; c < 2; c++) {
            int ch = wave + c * 4;
            gl2lds16(Ag + (size_t)(ch * 16) * K + k0, &As[ch * 512]);
        }
#pragma unroll
        for (int c = 0; c < NBCH / 4; c++) {
            int ch = wave + c * 4;
            gl2lds16(Bg + (size_t)(ch * 16) * K + k0, &Bs[ch * 512]);
        }
        __syncthreads();
        bhalf8 af[MI], bf[NI];
#pragma unroll
        for (int mi = 0; mi < MI; mi++) af[mi] = *(bhalf8*)&As[(wr * WM + mi * 16 + l16) * 32 + quad * 8];
#pragma unroll
        for (int ni = 0; ni < NI; ni++) bf[ni] = *(bhalf8*)&Bs[(wc * WN + ni * 16 + l16) * 32 + quad * 8];
#pragma unroll
        for (int mi = 0; mi < MI; mi++)
#pragma unroll
            for (int ni = 0; ni < NI; ni++)
                acc[mi][ni] = MFMA16(af[mi], bf[ni], acc[mi][ni]);
    }

#pragma unroll
    for (int mi = 0; mi < MI; mi++)
#pragma unroll
        for (int ni = 0; ni < NI; ni++) {
            f32x4 a = acc[mi][ni];
            int gc = n0 + wc * WN + ni * 16 + l16;
            float bsv = bias[gc];
            int gr0 = m0 + wr * WM + mi * 16 + quad * 4;
            if (mode == 0) {
                int mm = gc >> 9, cc = gc & 511;
                int hh = cc >> 6, e = cc & 63;
                int b = gr0 >> 11, s0 = gr0 & 2047;
                if (mm == 2) {
                    u64t pk = 0;
#pragma unroll
                    for (int r = 0; r < 4; r++) pk |= (u64t)f2b(a[r] + bsv) << (16 * r);
                    *(u64t*)&vtd[((size_t)(b * HH + hh) * HD + e) * SS + s0] = pk;
                } else {
                    u16* dst = (mm == 0) ? qd : kd;
#pragma unroll
                    for (int r = 0; r < 4; r++)
                        dst[((size_t)(b * HH + hh) * SS + s0 + r) * HD + e] = f2b(a[r] + bsv);
                }
            } else if (mode == 1) {
#pragma unroll
                for (int r = 0; r < 4; r++) {
                    size_t idx = (size_t)(gr0 + r) * N + gc;
                    outF[idx] = a[r] + bsv + resid[idx];
                }
            } else {
#pragma unroll
                for (int r = 0; r < 4; r++)
                    outB[(size_t)(gr0 + r) * N + gc] = f2b(fmaxf(a[r] + bsv, 0.0f));
            }
        }
}

// ---------------------------------------------------------------------------
// Flash attention: grid (16 bh, 32 q-tiles of 64); 4 waves x 16 q rows.
// q,k bf16 [bh,S,64]; vt bf16 [bh,64,S] (pre-transposed by QKV GEMM epilogue).
// ---------------------------------------------------------------------------
__global__ __launch_bounds__(256) void k_attention(const u16* __restrict__ q,
                                                   const u16* __restrict__ k,
                                                   const u16* __restrict__ vt,
                                                   u16* __restrict__ o) {
    __shared__ u16 Ks[64 * 72];       // [kv][hd]+pad
    __shared__ u16 Vs[64 * 72];       // [hd][kv]+pad
    __shared__ u16 Pw[4][16 * 72];
    int bh = blockIdx.x, qt = blockIdx.y;
    int t = threadIdx.x, wave = t >> 6, lane = t & 63, quad = lane >> 4, l16 = lane & 15;
    const u16* qb = q  + (size_t)bh * SS * HD;
    const u16* kb = k  + (size_t)bh * SS * HD;
    const u16* vb = vt + (size_t)bh * HD * SS;

    int srow = qt * 64 + wave * 16 + l16;
    bhalf8 qf0 = *(const bhalf8*)(qb + (size_t)srow * HD + quad * 8);
    bhalf8 qf1 = *(const bhalf8*)(qb + (size_t)srow * HD + 32 + quad * 8);

    f32x4 oacc[4] = {};
    float mrun[4], lrun[4];
#pragma unroll
    for (int r = 0; r < 4; r++) { mrun[r] = -1e30f; lrun[r] = 0.f; }

    int sr = t >> 2, sc = (t & 3) * 16;
    const u16* kptr = kb + (size_t)sr * HD + sc;    // K rows: [kv][hd]
    const u16* vptr = vb + (size_t)sr * SS + sc;    // Vt rows: [hd][kv]
    u16* ksl = &Ks[sr * 72 + sc];
    u16* vsl = &Vs[sr * 72 + sc];
    u16* pw = &Pw[wave][0];

    for (int kv0 = 0; kv0 < SS; kv0 += 64) {
        __syncthreads();
        bhalf8 ka  = *(const bhalf8*)(kptr + (size_t)kv0 * HD);
        bhalf8 ka2 = *(const bhalf8*)(kptr + (size_t)kv0 * HD + 8);
        bhalf8 va  = *(const bhalf8*)(vptr + kv0);
        bhalf8 va2 = *(const bhalf8*)(vptr + kv0 + 8);
        *(bhalf8*)ksl = ka;  *(bhalf8*)(ksl + 8) = ka2;
        *(bhalf8*)vsl = va;  *(bhalf8*)(vsl + 8) = va2;
        __syncthreads();

        f32x4 sacc[4] = {};
#pragma unroll
        for (int nt = 0; nt < 4; nt++) {
            bhalf8 kf0 = *(bhalf8*)&Ks[(nt * 16 + l16) * 72 + quad * 8];
            bhalf8 kf1 = *(bhalf8*)&Ks[(nt * 16 + l16) * 72 + 32 + quad * 8];
            sacc[nt] = MFMA16(qf0, kf0, sacc[nt]);
            sacc[nt] = MFMA16(qf1, kf1, sacc[nt]);
        }

        float tmax[4], rsum[4], alpha[4];
#pragma unroll
        for (int r = 0; r < 4; r++)
            tmax[r] = fmaxf(fmaxf(sacc[0][r], sacc[1][r]), fmaxf(sacc[2][r], sacc[3][r]));
#pragma unroll
        for (int m = 1; m < 16; m <<= 1)
#pragma unroll
            for (int r = 0; r < 4; r++) tmax[r] = fmaxf(tmax[r], __shfl_xor(tmax[r], m));
#pragma unroll
        for (int r = 0; r < 4; r++) {
            float mn = fmaxf(mrun[r], tmax[r]);
            alpha[r] = __expf(mrun[r] - mn);
            mrun[r] = mn;
            rsum[r] = 0.f;
        }
#pragma unroll
        for (int nt = 0; nt < 4; nt++)
#pragma unroll
            for (int r = 0; r < 4; r++) {
                float p = __expf(sacc[nt][r] - mrun[r]);
                sacc[nt][r] = p;
                rsum[r] += p;
            }
#pragma unroll
        for (int m = 1; m < 16; m <<= 1)
#pragma unroll
            for (int r = 0; r < 4; r++) rsum[r] += __shfl_xor(rsum[r], m);
#pragma unroll
        for (int r = 0; r < 4; r++) lrun[r] = lrun[r] * alpha[r] + rsum[r];
#pragma unroll
        for (int et = 0; et < 4; et++)
#pragma unroll
            for (int r = 0; r < 4; r++) oacc[et][r] *= alpha[r];

        // P: C-layout -> LDS (wave-local) -> A-layout
#pragma unroll
        for (int nt = 0; nt < 4; nt++)
#pragma unroll
            for (int r = 0; r < 4; r++)
                pw[(quad * 4 + r) * 72 + nt * 16 + l16] = f2b(sacc[nt][r]);
        asm volatile("s_waitcnt lgkmcnt(0)" ::: "memory");

#pragma unroll
        for (int ks = 0; ks < 2; ks++) {
            bhalf8 pa = *(bhalf8*)&pw[l16 * 72 + ks * 32 + quad * 8];
#pragma unroll
            for (int et = 0; et < 4; et++) {
                bhalf8 vf = *(bhalf8*)&Vs[(et * 16 + l16) * 72 + ks * 32 + quad * 8];
                oacc[et] = MFMA16(pa, vf, oacc[et]);
            }
        }
    }

    int b = bh >> 3, h = bh & 7;
    float inv[4];
#pragma unroll
    for (int r = 0; r < 4; r++) inv[r] = 1.0f / lrun[r];
#pragma unroll
    for (int et = 0; et < 4; et++)
#pragma unroll
        for (int r = 0; r < 4; r++) {
            int s = qt * 64 + wave * 16 + quad * 4 + r;
            int col = h * HD + et * 16 + l16;
            o[((size_t)b * SS + s) * DD + col] = f2b(oacc[et][r] * inv[r]);
        }
}

// ---------------------------------------------------------------------------
extern "C" void kernel_launch(void* const* d_in, const int* in_sizes, int n_in,
                              void* d_out, int out_size, void* d_ws, size_t ws_size,
                              hipStream_t stream) {
    const float* x   = (const float*)d_in[0];
    const float* Wq  = (const float*)d_in[1];
    const float* bq  = (const float*)d_in[2];
    const float* Wk  = (const float*)d_in[3];
    const float* bk  = (const float*)d_in[4];
    const float* Wv  = (const float*)d_in[5];
    const float* bv  = (const float*)d_in[6];
    const float* Wp  = (const float*)d_in[7];
    const float* bp  = (const float*)d_in[8];
    const float* W1  = (const float*)d_in[9];
    const float* b1  = (const float*)d_in[10];
    const float* W2  = (const float*)d_in[11];
    const float* b2  = (const float*)d_in[12];
    const float* g1  = (const float*)d_in[13];
    const float* be1 = (const float*)d_in[14];
    const float* g2  = (const float*)d_in[15];
    const float* be2 = (const float*)d_in[16];

    char* ws = (char*)d_ws;
    u16*   WqkvT   = (u16*)(ws + 0);                    // 1,572,864
    u16*   WpT     = (u16*)(ws + 1572864);              //   524,288
    u16*   W1T     = (u16*)(ws + 2097152);              // 2,097,152
    u16*   W2T     = (u16*)(ws + 4194304);              // 2,097,152
    float* biasqkv = (float*)(ws + 6291456);            // 6,144
    u16*   xn      = (u16*)(ws + 6297600);              // 4,194,304
    u16*   qB      = (u16*)(ws + 10491904);             // 4,194,304
    u16*   kB      = (u16*)(ws + 14686208);             // 4,194,304
    u16*   vTb     = (u16*)(ws + 18880512);             // 4,194,304  [bh,hd,S]
    u16*   oc      = (u16*)(ws + 23074816);             // 4,194,304
    float* x1      = (float*)(ws + 27269120);           // 8,388,608
    u16*   xn2     = (u16*)(ws + 35657728);             // 4,194,304
    u16*   hbuf    = (u16*)(ws + 39852032);             // 16,777,216 (end 56,629,248)

    // weight prep: one fused launch
    k_prep<<<3078, dim3(32, 8), 0, stream>>>(Wq, Wk, Wv, Wp, W1, W2, bq, bk, bv,
                                             WqkvT, WpT, W1T, W2T, biasqkv);
    // LN1
    k_layernorm<<<NT / 4, 256, 0, stream>>>(x, g1, be1, xn);
    // QKV projection (M=4096,N=1536,K=512) -> q,k [bh,s,hd]; v transposed [bh,hd,s]
    k_gemm<128, 2, 2, 4, 4><<<dim3(12, 32), 256, 0, stream>>>(xn, WqkvT, biasqkv, NT, 1536, 512, 0,
                                                              nullptr, nullptr, nullptr, qB, kB, vTb);
    // attention
    k_attention<<<dim3(BB * HH, SS / 64), 256, 0, stream>>>(qB, kB, vTb, oc);
    // output projection + residual -> x1 fp32
    k_gemm<64, 4, 1, 2, 4><<<dim3(8, 32), 256, 0, stream>>>(oc, WpT, bp, NT, 512, 512, 1,
                                                            x, x1, nullptr, nullptr, nullptr, nullptr);
    // LN2
    k_layernorm<<<NT / 4, 256, 0, stream>>>(x1, g2, be2, xn2);
    // MLP1: relu(xn2 @ W1 + b1) -> bf16
    k_gemm<128, 2, 2, 4, 4><<<dim3(16, 32), 256, 0, stream>>>(xn2, W1T, b1, NT, 2048, 512, 2,
                                                              nullptr, nullptr, hbuf, nullptr, nullptr, nullptr);
    // MLP2: x1 + hbuf @ W2 + b2 -> d_out fp32
    k_gemm<64, 4, 1, 2, 4><<<dim3(8, 32), 256, 0, stream>>>(hbuf, W2T, b2, NT, 512, 2048, 1,
                                                            x1, (float*)d_out, nullptr, nullptr, nullptr, nullptr);
}